// Round 1
// baseline (150.105 us; speedup 1.0000x reference)
//
#include <hip/hip_runtime.h>

#define DIM 128
#define NN 72
#define BB 2
#define NROWS (BB*NN*NN)   // 10368
#define BN (BB*NN)         // 144

// ---------------------------------------------------------------------------
// Kernel A: z[r][e] = sum_d path[r][d] * W_hz[d][e] + b_hz[e]
// 256 threads: lane e2 = t&63 owns 2 output cols (float2); rg = t>>6 picks
// the wave's row group (wave-uniform). 32 rows/block, W_hz staged in 64KB LDS.
// ---------------------------------------------------------------------------
__global__ __launch_bounds__(256) void k_gemm_z(const float* __restrict__ path,
                                                const float* __restrict__ Whz,
                                                const float* __restrict__ bhz,
                                                float* __restrict__ z) {
    __shared__ float Wl[DIM * DIM];   // 64 KB exactly
    {
        const float4* Wg = (const float4*)Whz;
        float4* Ws = (float4*)Wl;
        for (int i = threadIdx.x; i < DIM * DIM / 4; i += 256) Ws[i] = Wg[i];
    }
    __syncthreads();
    const int t  = threadIdx.x;
    const int e2 = t & 63;   // 2 cols per lane -> 128 cols per wave
    const int rg = t >> 6;   // 0..3, uniform within wave
    const int r0 = blockIdx.x * 32;

    float2 bz = *(const float2*)&bhz[2 * e2];
    float2 acc[8];
#pragma unroll
    for (int r = 0; r < 8; r++) acc[r] = bz;

    for (int d4 = 0; d4 < DIM / 4; d4++) {
        float4 p[8];
#pragma unroll
        for (int r = 0; r < 8; r++)
            p[r] = *(const float4*)&path[(r0 + rg + 4 * r) * DIM + 4 * d4];
#pragma unroll
        for (int dd = 0; dd < 4; dd++) {
            float2 w = *(const float2*)&Wl[(4 * d4 + dd) * DIM + 2 * e2];
#pragma unroll
            for (int r = 0; r < 8; r++) {
                float pv = ((const float*)&p[r])[dd];
                acc[r].x = fmaf(pv, w.x, acc[r].x);
                acc[r].y = fmaf(pv, w.y, acc[r].y);
            }
        }
    }
#pragma unroll
    for (int r = 0; r < 8; r++)
        *(float2*)&z[(r0 + rg + 4 * r) * DIM + 2 * e2] = acc[r];
}

// ---------------------------------------------------------------------------
// Kernel D: P1[m][e] = node[m]@W_zz[0:128], P3[m][e] = node[m]@W_zz[256:384]
// ---------------------------------------------------------------------------
__global__ __launch_bounds__(128) void k_node(const float* __restrict__ node,
                                              const float* __restrict__ Wzz,
                                              float* __restrict__ P1,
                                              float* __restrict__ P3) {
    __shared__ float row[DIM];
    const int m = blockIdx.x;
    const int e = threadIdx.x;
    row[e] = node[m * DIM + e];
    __syncthreads();
    float a1 = 0.f, a3 = 0.f;
    const float* W1 = Wzz;
    const float* W3 = Wzz + 2 * DIM * DIM;
    for (int d = 0; d < DIM; d++) {
        float pv = row[d];
        a1 = fmaf(pv, W1[d * DIM + e], a1);
        a3 = fmaf(pv, W3[d * DIM + e], a3);
    }
    P1[m * DIM + e] = a1;
    P3[m * DIM + e] = a3;
}

// ---------------------------------------------------------------------------
// Kernel B: zmax[b,i,j,d] = max( max_k z[b,i,k,d]+z[b,k,j,d], z[b,i,j,d] )
// 128 threads = d lanes; 4x4 (i,j) tile per block; grid = 2*18*18 = 648.
// ---------------------------------------------------------------------------
__global__ __launch_bounds__(128) void k_trop(const float* __restrict__ z,
                                              float* __restrict__ zmax) {
    const int blk = blockIdx.x;
    const int b   = blk / 324;
    const int rem = blk - b * 324;
    const int it  = rem / 18;
    const int jt  = rem - it * 18;
    const int i0 = it * 4, j0 = jt * 4;
    const int d = threadIdx.x;
    const float* zb = z + b * NN * NN * DIM;

    float acc[4][4];
#pragma unroll
    for (int a = 0; a < 4; a++)
#pragma unroll
        for (int c = 0; c < 4; c++) acc[a][c] = -3.402823466e38f;

    for (int k = 0; k < NN; k++) {
        float zi[4], zj[4];
#pragma unroll
        for (int a = 0; a < 4; a++) zi[a] = zb[((i0 + a) * NN + k) * DIM + d];
#pragma unroll
        for (int c = 0; c < 4; c++) zj[c] = zb[(k * NN + (j0 + c)) * DIM + d];
#pragma unroll
        for (int a = 0; a < 4; a++)
#pragma unroll
            for (int c = 0; c < 4; c++)
                acc[a][c] = fmaxf(acc[a][c], zi[a] + zj[c]);
    }

    float* zmb = zmax + b * NN * NN * DIM;
#pragma unroll
    for (int a = 0; a < 4; a++)
#pragma unroll
        for (int c = 0; c < 4; c++) {
            int idx = ((i0 + a) * NN + (j0 + c)) * DIM + d;
            zmb[idx] = fmaxf(acc[a][c], zb[idx]);
        }
}

// ---------------------------------------------------------------------------
// Kernel C: out[r][e] = relu( zmax[r]@W2 + P1[b*N+i][e] + P3[b*N+j][e] + b_zz[e] )
// Same GEMM structure as kernel A.  NOTE: zin aliases out (zmax lives in
// d_out); safe because each block reads only the rows it later writes, and
// all reads precede all writes in each thread.  No __restrict__ on those two.
// ---------------------------------------------------------------------------
__global__ __launch_bounds__(256) void k_out(const float* zin,
                                             const float* __restrict__ Wzz,
                                             const float* __restrict__ bzz,
                                             const float* __restrict__ P1,
                                             const float* __restrict__ P3,
                                             float* out) {
    __shared__ float Wl[DIM * DIM];   // W2 = W_zz rows 128..255
    {
        const float4* Wg = (const float4*)(Wzz + DIM * DIM);
        float4* Ws = (float4*)Wl;
        for (int i = threadIdx.x; i < DIM * DIM / 4; i += 256) Ws[i] = Wg[i];
    }
    __syncthreads();
    const int t  = threadIdx.x;
    const int e2 = t & 63;
    const int rg = t >> 6;
    const int r0 = blockIdx.x * 32;

    float2 acc[8];
#pragma unroll
    for (int r = 0; r < 8; r++) acc[r] = make_float2(0.f, 0.f);

    for (int d4 = 0; d4 < DIM / 4; d4++) {
        float4 p[8];
#pragma unroll
        for (int r = 0; r < 8; r++)
            p[r] = *(const float4*)&zin[(r0 + rg + 4 * r) * DIM + 4 * d4];
#pragma unroll
        for (int dd = 0; dd < 4; dd++) {
            float2 w = *(const float2*)&Wl[(4 * d4 + dd) * DIM + 2 * e2];
#pragma unroll
            for (int r = 0; r < 8; r++) {
                float pv = ((const float*)&p[r])[dd];
                acc[r].x = fmaf(pv, w.x, acc[r].x);
                acc[r].y = fmaf(pv, w.y, acc[r].y);
            }
        }
    }

    float2 bz = *(const float2*)&bzz[2 * e2];
#pragma unroll
    for (int r = 0; r < 8; r++) {
        int row = r0 + rg + 4 * r;
        int bi  = row / NN;              // = b*NN + i
        int b   = row / (NN * NN);
        int j   = row - (row / NN) * NN; // row % NN
        int p3r = b * NN + j;
        float2 v1 = *(const float2*)&P1[bi * DIM + 2 * e2];
        float2 v3 = *(const float2*)&P3[p3r * DIM + 2 * e2];
        float ox = fmaxf(acc[r].x + v1.x + v3.x + bz.x, 0.f);
        float oy = fmaxf(acc[r].y + v1.y + v3.y + bz.y, 0.f);
        *(float2*)&out[row * DIM + 2 * e2] = make_float2(ox, oy);
    }
}

extern "C" void kernel_launch(void* const* d_in, const int* in_sizes, int n_in,
                              void* d_out, int out_size, void* d_ws, size_t ws_size,
                              hipStream_t stream) {
    const float* node = (const float*)d_in[0];   // (144,128)
    const float* path = (const float*)d_in[1];   // (2,72,72,128)
    const float* Whz  = (const float*)d_in[2];   // (128,128)
    const float* bhz  = (const float*)d_in[3];   // (128,)
    const float* Wzz  = (const float*)d_in[4];   // (384,128)
    const float* bzz  = (const float*)d_in[5];   // (128,)
    float* out = (float*)d_out;

    float* z  = (float*)d_ws;            // NROWS*DIM floats = 5.3 MB
    float* P1 = z + NROWS * DIM;         // 144*128
    float* P3 = P1 + BN * DIM;           // 144*128
    float* zmax = out;                   // reuse d_out as zmax scratch

    hipLaunchKernelGGL(k_gemm_z, dim3(NROWS / 32), dim3(256), 0, stream, path, Whz, bhz, z);
    hipLaunchKernelGGL(k_node,   dim3(BN),         dim3(128), 0, stream, node, Wzz, P1, P3);
    hipLaunchKernelGGL(k_trop,   dim3(BB * 18 * 18), dim3(128), 0, stream, z, zmax);
    hipLaunchKernelGGL(k_out,    dim3(NROWS / 32), dim3(256), 0, stream, zmax, Wzz, bzz, P1, P3, out);
}

// Round 3
// 114.331 us; speedup vs baseline: 1.3129x; 1.3129x over previous
//
#include <hip/hip_runtime.h>

#define DIM 128
#define NN 72
#define BB 2
#define NROWS (BB*NN*NN)   // 10368
#define BN (BB*NN)         // 144
#define ZBLOCKS (NROWS/16) // 648

// ---------------------------------------------------------------------------
// Kernel 1: fused  z = path@W_hz + b_hz   (blocks 0..647, 16 rows each)
//           and    P1/P3 = node@W1 / node@W3  (blocks 648..665, 8 rows each)
// Pattern: stage input rows in LDS (coalesced), stream W from L2 (coalesced,
// software-pipelined one d4-chunk ahead), acc in registers.
// ---------------------------------------------------------------------------
__global__ __launch_bounds__(256) void k_phase1(const float* __restrict__ path,
                                                const float* __restrict__ Whz,
                                                const float* __restrict__ bhz,
                                                float* __restrict__ z,
                                                const float* __restrict__ node,
                                                const float* __restrict__ Wzz,
                                                float* __restrict__ P1,
                                                float* __restrict__ P3) {
    __shared__ float rows[16 * DIM];   // 8 KB
    const int t = threadIdx.x;

    if (blockIdx.x < ZBLOCKS) {
        const int r0 = blockIdx.x * 16;
        {
            float4* rs = (float4*)rows;
            const float4* pg = (const float4*)(path + r0 * DIM);
            rs[t]       = pg[t];
            rs[t + 256] = pg[t + 256];
        }
        __syncthreads();

        const int e2 = t & 63;   // 2 output cols per lane
        const int rg = t >> 6;   // 0..3 wave-uniform row offset
        float2 bz = *(const float2*)&bhz[2 * e2];
        float2 acc[4];
#pragma unroll
        for (int r = 0; r < 4; r++) acc[r] = bz;

        const float* Wp = Whz + 2 * e2;
        float2 w[4], wn[4];
#pragma unroll
        for (int dd = 0; dd < 4; dd++) w[dd] = *(const float2*)&Wp[dd * DIM];

        for (int d4 = 0; d4 < DIM / 4; d4++) {
            if (d4 < DIM / 4 - 1) {
#pragma unroll
                for (int dd = 0; dd < 4; dd++)
                    wn[dd] = *(const float2*)&Wp[(4 * d4 + 4 + dd) * DIM];
            }
            float4 pr[4];
#pragma unroll
            for (int r = 0; r < 4; r++)
                pr[r] = *(const float4*)&rows[(rg + 4 * r) * DIM + 4 * d4];
#pragma unroll
            for (int dd = 0; dd < 4; dd++)
#pragma unroll
                for (int r = 0; r < 4; r++) {
                    float pv = ((const float*)&pr[r])[dd];
                    acc[r].x = fmaf(pv, w[dd].x, acc[r].x);
                    acc[r].y = fmaf(pv, w[dd].y, acc[r].y);
                }
#pragma unroll
            for (int dd = 0; dd < 4; dd++) w[dd] = wn[dd];
        }
#pragma unroll
        for (int r = 0; r < 4; r++)
            *(float2*)&z[(r0 + rg + 4 * r) * DIM + 2 * e2] = acc[r];
    } else {
        // node GEMM: 18 blocks x 8 rows
        const int r0 = (blockIdx.x - ZBLOCKS) * 8;
        {
            float4* rs = (float4*)rows;
            const float4* ng = (const float4*)(node + r0 * DIM);
            rs[t] = ng[t];   // 8*128 floats = 256 float4
        }
        __syncthreads();
        const int e  = t & 127;
        const int rr = t >> 7;   // 0..1
        float a1[4] = {0.f, 0.f, 0.f, 0.f};
        float a3[4] = {0.f, 0.f, 0.f, 0.f};
        const float* W1 = Wzz + e;
        const float* W3 = Wzz + 2 * DIM * DIM + e;
        for (int d = 0; d < DIM; d++) {
            float w1 = W1[d * DIM];
            float w3 = W3[d * DIM];
#pragma unroll
            for (int s = 0; s < 4; s++) {
                float pv = rows[(rr + 2 * s) * DIM + d];
                a1[s] = fmaf(pv, w1, a1[s]);
                a3[s] = fmaf(pv, w3, a3[s]);
            }
        }
#pragma unroll
        for (int s = 0; s < 4; s++) {
            int m = r0 + rr + 2 * s;
            P1[m * DIM + e] = a1[s];
            P3[m * DIM + e] = a3[s];
        }
    }
}

// ---------------------------------------------------------------------------
// Kernel 2: tropical conv, 4x4 (i,j) tile, d across 128 lanes, 2-way k-split
// across ty with LDS merge; k+1 prefetch pipeline.
// BUGFIX vs R2: output write now includes the batch offset (zmb, not zmax).
// ---------------------------------------------------------------------------
__global__ __launch_bounds__(256) void k_trop(const float* __restrict__ z,
                                              float* __restrict__ zmax) {
    __shared__ float comb[16 * DIM];   // 8 KB
    const int blk = blockIdx.x;
    const int b   = blk / 324;
    const int rem = blk - b * 324;
    const int it  = rem / 18;
    const int jt  = rem - it * 18;
    const int i0 = it * 4, j0 = jt * 4;
    const int t  = threadIdx.x;
    const int d  = t & 127;
    const int ty = t >> 7;    // k parity
    const float* zb = z + b * NN * NN * DIM;

    float acc[16];
#pragma unroll
    for (int q = 0; q < 16; q++) acc[q] = -3.402823466e38f;

    float zi[4], zj[4], zin[4], zjn[4];
    int k = ty;
#pragma unroll
    for (int a = 0; a < 4; a++) zi[a] = zb[((i0 + a) * NN + k) * DIM + d];
#pragma unroll
    for (int c = 0; c < 4; c++) zj[c] = zb[(k * NN + (j0 + c)) * DIM + d];

    for (int it2 = 0; it2 < NN / 2; it2++) {
        int kn = k + 2;
        if (it2 < NN / 2 - 1) {
#pragma unroll
            for (int a = 0; a < 4; a++) zin[a] = zb[((i0 + a) * NN + kn) * DIM + d];
#pragma unroll
            for (int c = 0; c < 4; c++) zjn[c] = zb[(kn * NN + (j0 + c)) * DIM + d];
        }
#pragma unroll
        for (int a = 0; a < 4; a++)
#pragma unroll
            for (int c = 0; c < 4; c++)
                acc[a * 4 + c] = fmaxf(acc[a * 4 + c], zi[a] + zj[c]);
#pragma unroll
        for (int a = 0; a < 4; a++) { zi[a] = zin[a]; zj[a] = zjn[a]; }
        k = kn;
    }

    if (ty == 1) {
#pragma unroll
        for (int q = 0; q < 16; q++) comb[q * DIM + d] = acc[q];
    }
    __syncthreads();
    if (ty == 0) {
        float* zmb = zmax + b * NN * NN * DIM;   // BUGFIX: batch offset
#pragma unroll
        for (int a = 0; a < 4; a++)
#pragma unroll
            for (int c = 0; c < 4; c++) {
                int q = a * 4 + c;
                float m = fmaxf(acc[q], comb[q * DIM + d]);
                int idx = ((i0 + a) * NN + (j0 + c)) * DIM + d;
                zmb[idx] = fmaxf(m, zb[idx]);
            }
    }
}

// ---------------------------------------------------------------------------
// Kernel 3: out = relu( zmax@W2 + P1[b,i] + P3[b,j] + b_zz ), 16 rows/block.
// zin aliases out (zmax lives in d_out): each block reads only its own 16
// rows into LDS before the barrier, writes them at the end — safe.
// ---------------------------------------------------------------------------
__global__ __launch_bounds__(256) void k_out(const float* zin,
                                             const float* __restrict__ Wzz,
                                             const float* __restrict__ bzz,
                                             const float* __restrict__ P1,
                                             const float* __restrict__ P3,
                                             float* out) {
    __shared__ float rows[16 * DIM];   // 8 KB
    const int t  = threadIdx.x;
    const int r0 = blockIdx.x * 16;
    {
        float4* rs = (float4*)rows;
        const float4* zg = (const float4*)(zin + r0 * DIM);
        rs[t]       = zg[t];
        rs[t + 256] = zg[t + 256];
    }
    __syncthreads();

    const int e2 = t & 63;
    const int rg = t >> 6;
    float2 acc[4];
#pragma unroll
    for (int r = 0; r < 4; r++) acc[r] = make_float2(0.f, 0.f);

    const float* Wp = Wzz + DIM * DIM + 2 * e2;   // W2 block
    float2 w[4], wn[4];
#pragma unroll
    for (int dd = 0; dd < 4; dd++) w[dd] = *(const float2*)&Wp[dd * DIM];

    for (int d4 = 0; d4 < DIM / 4; d4++) {
        if (d4 < DIM / 4 - 1) {
#pragma unroll
            for (int dd = 0; dd < 4; dd++)
                wn[dd] = *(const float2*)&Wp[(4 * d4 + 4 + dd) * DIM];
        }
        float4 pr[4];
#pragma unroll
        for (int r = 0; r < 4; r++)
            pr[r] = *(const float4*)&rows[(rg + 4 * r) * DIM + 4 * d4];
#pragma unroll
        for (int dd = 0; dd < 4; dd++)
#pragma unroll
            for (int r = 0; r < 4; r++) {
                float pv = ((const float*)&pr[r])[dd];
                acc[r].x = fmaf(pv, w[dd].x, acc[r].x);
                acc[r].y = fmaf(pv, w[dd].y, acc[r].y);
            }
#pragma unroll
        for (int dd = 0; dd < 4; dd++) w[dd] = wn[dd];
    }

    float2 bz = *(const float2*)&bzz[2 * e2];
#pragma unroll
    for (int r = 0; r < 4; r++) {
        int row = r0 + rg + 4 * r;
        int bi  = row / NN;
        int b   = row / (NN * NN);
        int j   = row - bi * NN;
        float2 v1 = *(const float2*)&P1[bi * DIM + 2 * e2];
        float2 v3 = *(const float2*)&P3[(b * NN + j) * DIM + 2 * e2];
        float ox = fmaxf(acc[r].x + v1.x + v3.x + bz.x, 0.f);
        float oy = fmaxf(acc[r].y + v1.y + v3.y + bz.y, 0.f);
        *(float2*)&out[row * DIM + 2 * e2] = make_float2(ox, oy);
    }
}

extern "C" void kernel_launch(void* const* d_in, const int* in_sizes, int n_in,
                              void* d_out, int out_size, void* d_ws, size_t ws_size,
                              hipStream_t stream) {
    const float* node = (const float*)d_in[0];
    const float* path = (const float*)d_in[1];
    const float* Whz  = (const float*)d_in[2];
    const float* bhz  = (const float*)d_in[3];
    const float* Wzz  = (const float*)d_in[4];
    const float* bzz  = (const float*)d_in[5];
    float* out = (float*)d_out;

    float* z  = (float*)d_ws;            // 10368*128 floats
    float* P1 = z + NROWS * DIM;
    float* P3 = P1 + BN * DIM;
    float* zmax = out;                   // d_out doubles as zmax scratch

    hipLaunchKernelGGL(k_phase1, dim3(ZBLOCKS + 18), dim3(256), 0, stream,
                       path, Whz, bhz, z, node, Wzz, P1, P3);
    hipLaunchKernelGGL(k_trop,   dim3(BB * 18 * 18), dim3(256), 0, stream, z, zmax);
    hipLaunchKernelGGL(k_out,    dim3(ZBLOCKS),      dim3(256), 0, stream,
                       zmax, Wzz, bzz, P1, P3, out);
}